// Round 5
// baseline (264.848 us; speedup 1.0000x reference)
//
#include <hip/hip_runtime.h>
#include <hip/hip_bf16.h>

#define DIM 1024
#define SEQ 4096
#define NB 4
#define MROWS (NB * SEQ)   // 16384
#define NC 64              // chunks per sequence
#define CL (SEQ / NC)      // 64 L-positions per chunk

// GEMM tiling
#define BM 256
#define BN 256
#define BK 32
#define NT (DIM / BK)      // 32 K-tiles
#define TILE_LDS 32768     // A half (16KB) + B half (16KB) per K-tile
#define GEMM_LDS (4 * TILE_LDS)   // 128 KiB, 4-buffer rotation

typedef __attribute__((ext_vector_type(8))) short bf16x8;
typedef __attribute__((ext_vector_type(4))) float f32x4;

static __device__ __forceinline__ unsigned short f2bf(float f) {
    union { float f; unsigned u; } v; v.f = f;
    unsigned r = v.u + 0x7FFF + ((v.u >> 16) & 1);
    return (unsigned short)(r >> 16);
}

static __device__ __forceinline__ float bf2f(unsigned short h) {
    union { unsigned u; float f; } v; v.u = ((unsigned)h) << 16;
    return v.f;
}

static __device__ __forceinline__ void gload_lds16(const void* g, void* l) {
    __builtin_amdgcn_global_load_lds((const __attribute__((address_space(1))) void*)g,
                                     (__attribute__((address_space(3))) void*)l, 16, 0, 0);
}

// ---- convert x and W fp32 -> bf16 ----
__global__ void convert_kernel(const float* __restrict__ x, const float* __restrict__ W,
                               unsigned short* __restrict__ xb, unsigned short* __restrict__ wb) {
    const long long NX4 = (long long)MROWS * DIM / 4;
    const long long NW4 = (long long)DIM * DIM / 4;
    long long t = (long long)blockIdx.x * blockDim.x + threadIdx.x;
    if (t < NX4) {
        float4 v = ((const float4*)x)[t];
        ushort4 o;
        o.x = f2bf(v.x); o.y = f2bf(v.y); o.z = f2bf(v.z); o.w = f2bf(v.w);
        ((ushort4*)xb)[t] = o;
    } else if (t < NX4 + NW4) {
        long long u = t - NX4;
        float4 v = ((const float4*)W)[u];
        ushort4 o;
        o.x = f2bf(v.x); o.y = f2bf(v.y); o.z = f2bf(v.z); o.w = f2bf(v.w);
        ((ushort4*)wb)[u] = o;
    }
}

// Stage one K-tile half (A or B) of a tile into buffer q.
// LDS linear [256 rows][64 B]; the 4 16B-slots of each row are stored XOR-permuted:
// LDS slot s holds global chunk s ^ ((row>>1)&3); staging thread's XOR term
// ((row>>1)&3) == ((lane>>3)&3) so the source chunk is lane-only. Zero-conflict
// on ds_read (verified round 4: SQ_LDS_BANK_CONFLICT = 0).
static __device__ __forceinline__ void stage_A(const unsigned short* __restrict__ A, char* smem,
                                               int q, int m0, int ks, int w, int lane) {
    const int c16 = (lane & 3) ^ ((lane >> 3) & 3);
#pragma unroll
    for (int r = 0; r < 2; ++r) {
        int row = r * 128 + w * 16 + (lane >> 2);
        const unsigned short* g = A + (size_t)(m0 + row) * DIM + ks + c16 * 8;
        char* l = smem + q * TILE_LDS + (r * 128 + w * 16) * 64 + lane * 16;
        gload_lds16(g, l);
    }
}

static __device__ __forceinline__ void stage_B(const unsigned short* __restrict__ Bm, char* smem,
                                               int q, int n0, int ks, int w, int lane) {
    const int c16 = (lane & 3) ^ ((lane >> 3) & 3);
#pragma unroll
    for (int r = 0; r < 2; ++r) {
        int row = r * 128 + w * 16 + (lane >> 2);
        const unsigned short* g = Bm + (size_t)(n0 + row) * DIM + ks + c16 * 8;
        char* l = smem + q * TILE_LDS + 16384 + (r * 128 + w * 16) * 64 + lane * 16;
        gload_lds16(g, l);
    }
}

// ---- GEMM: V[m][n] = bf16( sum_k A[m][k]*B[n][k] + bias[n] ) ----
// 256x256 tile, BK=32, 4-deep LDS rotation, counted vmcnt(8), one barrier per
// K-tile (loose schedule: compiler interleaves ds_read/MFMA with fine lgkmcnt).
__global__ __launch_bounds__(512, 2) void gemm_kernel(const unsigned short* __restrict__ A,
                                                      const unsigned short* __restrict__ Bm,
                                                      const float* __restrict__ bias,
                                                      unsigned short* __restrict__ V) {
    extern __shared__ char smem[];
    const int tid  = threadIdx.x;
    const int lane = tid & 63;
    const int w    = tid >> 6;           // wave 0..7
    const int wm   = w >> 2;             // 0..1
    const int wn   = w & 3;              // 0..3
    const int wr   = wm * 128;           // wave row offset (M)
    const int wc   = wn * 64;            // wave col offset (N)
    const int rl   = lane & 15;
    const int rh   = lane >> 4;
    const int swz  = (rh ^ ((rl >> 1) & 3)) * 16;  // undo stored XOR permutation
    const int m0   = blockIdx.x * BM;
    const int n0   = blockIdx.y * BN;

    f32x4 acc[8][4];
#pragma unroll
    for (int m = 0; m < 8; ++m)
#pragma unroll
        for (int n = 0; n < 4; ++n)
            acc[m][n] = (f32x4){0.f, 0.f, 0.f, 0.f};

    float bv[4];
#pragma unroll
    for (int nf = 0; nf < 4; ++nf)
        bv[nf] = bias[n0 + wc + nf * 16 + rl];

    // prologue: stage tiles 0,1,2 (12 loads/thread in flight)
#pragma unroll
    for (int s = 0; s < 3; ++s) {
        stage_A(A, smem, s, m0, s * BK, w, lane);
        stage_B(Bm, smem, s, n0, s * BK, w, lane);
    }

#pragma unroll 4
    for (int t = 0; t < NT; ++t) {
        const int q  = t & 3;
        const int qn = (t + 3) & 3;
        const int ksn = ((t + 3) & (NT - 1)) * BK;   // tail wraps into dead buffers
        // tile t resident: own oldest 4 loads landed + all waves past barrier
        asm volatile("s_waitcnt vmcnt(8)" ::: "memory");
        __builtin_amdgcn_s_barrier();
        char* base = smem + q * TILE_LDS;

        bf16x8 bfr[4];
#pragma unroll
        for (int nf = 0; nf < 4; ++nf)
            bfr[nf] = *(const bf16x8*)(base + 16384 + (wc + nf * 16 + rl) * 64 + swz);
        bf16x8 af[4];
#pragma unroll
        for (int mf = 0; mf < 4; ++mf)
            af[mf] = *(const bf16x8*)(base + (wr + mf * 16 + rl) * 64 + swz);
        stage_A(A, smem, qn, m0, ksn, w, lane);
        __builtin_amdgcn_s_setprio(1);
#pragma unroll
        for (int mf = 0; mf < 4; ++mf)
#pragma unroll
            for (int nf = 0; nf < 4; ++nf)
                acc[mf][nf] = __builtin_amdgcn_mfma_f32_16x16x32_bf16(af[mf], bfr[nf], acc[mf][nf], 0, 0, 0);
        __builtin_amdgcn_s_setprio(0);

#pragma unroll
        for (int mf = 0; mf < 4; ++mf)
            af[mf] = *(const bf16x8*)(base + (wr + (mf + 4) * 16 + rl) * 64 + swz);
        stage_B(Bm, smem, qn, n0, ksn, w, lane);
        __builtin_amdgcn_s_setprio(1);
#pragma unroll
        for (int mf = 0; mf < 4; ++mf)
#pragma unroll
            for (int nf = 0; nf < 4; ++nf)
                acc[mf + 4][nf] = __builtin_amdgcn_mfma_f32_16x16x32_bf16(af[mf], bfr[nf], acc[mf + 4][nf], 0, 0, 0);
        __builtin_amdgcn_s_setprio(0);
    }

    // epilogue: C/D layout col = lane&15, row = (lane>>4)*4 + reg; store bf16
#pragma unroll
    for (int mf = 0; mf < 8; ++mf) {
#pragma unroll
        for (int nf = 0; nf < 4; ++nf) {
            int gcol = n0 + wc + nf * 16 + rl;
#pragma unroll
            for (int j = 0; j < 4; ++j) {
                int grow = m0 + wr + mf * 16 + rh * 4 + j;
                V[(size_t)grow * DIM + gcol] = f2bf(acc[mf][nf][j] + bv[nf]);
            }
        }
    }
}

// ---- fused scan: per-chunk aggregate -> decoupled lookback -> emit ----
// grid = NB*NC blocks (one per (batch,chunk)), 256 threads, 4 e-cols/thread.
// flags[b*NC+c]: 0 = none, 1 = aggregate published, 2 = inclusive prefix published.
__global__ __launch_bounds__(256) void scan_kernel(const unsigned short* __restrict__ vb,
                                                   const float* __restrict__ ph,
                                                   float* __restrict__ aggR, float* __restrict__ aggI,
                                                   float* __restrict__ preR, float* __restrict__ preI,
                                                   int* __restrict__ flags,
                                                   float* __restrict__ out) {
    const int tid = threadIdx.x;
    const int c   = blockIdx.x & (NC - 1);
    const int b   = blockIdx.x >> 6;          // NC == 64
    const int l0  = c * CL;
    const int e0  = tid * 4;
    const size_t vbase = ((size_t)b * SEQ + l0) * DIM + e0;
    const size_t pbase = (size_t)l0 * DIM + e0;

    // pass 1: chunk aggregate
    float ar[4] = {0.f, 0.f, 0.f, 0.f}, ai[4] = {0.f, 0.f, 0.f, 0.f};
    for (int l = 0; l < CL; ++l) {
        ushort4 vv = *(const ushort4*)(vb + vbase + (size_t)l * DIM);
        float4  pp = *(const float4*)(ph + pbase + (size_t)l * DIM);
        float v[4] = {bf2f(vv.x), bf2f(vv.y), bf2f(vv.z), bf2f(vv.w)};
        float p[4] = {pp.x, pp.y, pp.z, pp.w};
#pragma unroll
        for (int k = 0; k < 4; ++k) {
            float s, cn;
            __sincosf(p[k], &s, &cn);
            ar[k] += v[k] * cn;
            ai[k] += v[k] * s;
        }
    }

    const size_t idx  = ((size_t)b * NC + c) * DIM + e0;
    const int    fidx = b * NC + c;
    if (c > 0) {
        *(float4*)(aggR + idx) = (float4){ar[0], ar[1], ar[2], ar[3]};
        *(float4*)(aggI + idx) = (float4){ai[0], ai[1], ai[2], ai[3]};
        __syncthreads();
        __threadfence();
        if (tid == 0)
            __hip_atomic_store(flags + fidx, 1, __ATOMIC_RELEASE, __HIP_MEMORY_SCOPE_AGENT);
    }

    // decoupled lookback: exclusive prefix over chunks < c
    float pr[4] = {0.f, 0.f, 0.f, 0.f}, pi[4] = {0.f, 0.f, 0.f, 0.f};
    if (c > 0) {
        int cc = c - 1;
        for (;;) {
            int st;
            do {
                st = __hip_atomic_load(flags + b * NC + cc, __ATOMIC_ACQUIRE, __HIP_MEMORY_SCOPE_AGENT);
            } while (st == 0);
            size_t cidx = ((size_t)b * NC + cc) * DIM + e0;
            if (st == 2) {
                float4 r  = *(const float4*)(preR + cidx);
                float4 im = *(const float4*)(preI + cidx);
                pr[0] += r.x;  pr[1] += r.y;  pr[2] += r.z;  pr[3] += r.w;
                pi[0] += im.x; pi[1] += im.y; pi[2] += im.z; pi[3] += im.w;
                break;
            }
            float4 r  = *(const float4*)(aggR + cidx);
            float4 im = *(const float4*)(aggI + cidx);
            pr[0] += r.x;  pr[1] += r.y;  pr[2] += r.z;  pr[3] += r.w;
            pi[0] += im.x; pi[1] += im.y; pi[2] += im.z; pi[3] += im.w;
            --cc;   // cc never goes below 0: flags[b*NC+0] becomes 2
        }
    }

    // publish inclusive prefix
    *(float4*)(preR + idx) = (float4){pr[0] + ar[0], pr[1] + ar[1], pr[2] + ar[2], pr[3] + ar[3]};
    *(float4*)(preI + idx) = (float4){pi[0] + ai[0], pi[1] + ai[1], pi[2] + ai[2], pi[3] + ai[3]};
    __syncthreads();
    __threadfence();
    if (tid == 0)
        __hip_atomic_store(flags + fidx, 2, __ATOMIC_RELEASE, __HIP_MEMORY_SCOPE_AGENT);

    // pass 2: running cumsum + retrieval + norm (vb/ph re-read mostly from L2)
    for (int l = 0; l < CL; ++l) {
        ushort4 vv = *(const ushort4*)(vb + vbase + (size_t)l * DIM);
        float4  pp = *(const float4*)(ph + pbase + (size_t)l * DIM);
        float v[4] = {bf2f(vv.x), bf2f(vv.y), bf2f(vv.z), bf2f(vv.w)};
        float p[4] = {pp.x, pp.y, pp.z, pp.w};
        float rn = rsqrtf((float)(l0 + l + 1));
        float o[4];
#pragma unroll
        for (int k = 0; k < 4; ++k) {
            float s, cn;
            __sincosf(p[k], &s, &cn);
            pr[k] += v[k] * cn;
            pi[k] += v[k] * s;
            o[k] = (pr[k] * cn + pi[k] * s) * rn;
        }
        *(float4*)(out + vbase + (size_t)l * DIM) = (float4){o[0], o[1], o[2], o[3]};
    }
}

extern "C" void kernel_launch(void* const* d_in, const int* in_sizes, int n_in,
                              void* d_out, int out_size, void* d_ws, size_t ws_size,
                              hipStream_t stream) {
    const float* x  = (const float*)d_in[0];
    const float* ph = (const float*)d_in[1];
    const float* W  = (const float*)d_in[2];
    const float* b  = (const float*)d_in[3];
    float* out = (float*)d_out;

    // d_out doubles as scratch for bf16 inputs until scan overwrites it
    unsigned short* xb = (unsigned short*)d_out;
    unsigned short* wb = xb + (size_t)MROWS * DIM;

    // ws: vb bf16 32MB | aggR 1MB | aggI 1MB | preR 1MB | preI 1MB | flags 1KB
    unsigned short* vb = (unsigned short*)d_ws;
    float* aggR = (float*)(vb + (size_t)MROWS * DIM);
    float* aggI = aggR + (size_t)NB * NC * DIM;
    float* preR = aggI + (size_t)NB * NC * DIM;
    float* preI = preR + (size_t)NB * NC * DIM;
    int*   flags = (int*)(preI + (size_t)NB * NC * DIM);

    (void)hipFuncSetAttribute((const void*)gemm_kernel,
                              hipFuncAttributeMaxDynamicSharedMemorySize, GEMM_LDS);

    // 0) zero the lookback flags (graph-capture-safe async memset)
    hipMemsetAsync(flags, 0, NB * NC * sizeof(int), stream);

    // 1) convert x, W to bf16 (into d_out scratch region)
    {
        long long total4 = (long long)MROWS * DIM / 4 + (long long)DIM * DIM / 4;
        int blocks = (int)((total4 + 255) / 256);
        convert_kernel<<<blocks, 256, 0, stream>>>(x, W, xb, wb);
    }
    // 2) GEMM -> bf16 value into ws
    {
        dim3 grid(MROWS / BM, DIM / BN);
        gemm_kernel<<<grid, 512, GEMM_LDS, stream>>>(xb, wb, b, vb);
    }
    // 3) fused chunk-scan + retrieval (replaces passA/passB/passC)
    scan_kernel<<<NB * NC, 256, 0, stream>>>(vb, ph, aggR, aggI, preR, preI, flags, out);
}

// Round 6
// 90.330 us; speedup vs baseline: 2.9320x; 2.9320x over previous
//
#include <hip/hip_runtime.h>
#include <hip/hip_bf16.h>

#define DIM 1024
#define SEQ 4096
#define NB 4
#define MROWS (NB * SEQ)   // 16384
#define NC 64              // chunks per sequence
#define CL (SEQ / NC)      // 64 L-positions per chunk

// GEMM tiling
#define BM 256
#define BN 256
#define BK 32
#define NT (DIM / BK)      // 32 K-tiles
#define TILE_LDS 32768     // A half (16KB) + B half (16KB) per K-tile
#define GEMM_LDS (4 * TILE_LDS)   // 128 KiB, 4-buffer rotation

typedef __attribute__((ext_vector_type(8))) short bf16x8;
typedef __attribute__((ext_vector_type(4))) float f32x4;

static __device__ __forceinline__ unsigned short f2bf(float f) {
    union { float f; unsigned u; } v; v.f = f;
    unsigned r = v.u + 0x7FFF + ((v.u >> 16) & 1);
    return (unsigned short)(r >> 16);
}

static __device__ __forceinline__ float bf2f(unsigned short h) {
    union { unsigned u; float f; } v; v.u = ((unsigned)h) << 16;
    return v.f;
}

// pack two fp32 -> one u32 holding (bf16(a) low, bf16(b) high), round-nearest-even
static __device__ __forceinline__ unsigned int bfpair(float a, float b) {
    unsigned ua = __float_as_uint(a), ub = __float_as_uint(b);
    unsigned ra = (ua + 0x7FFF + ((ua >> 16) & 1)) >> 16;
    unsigned rb = (ub + 0x7FFF + ((ub >> 16) & 1)) & 0xFFFF0000u;
    return ra | rb;
}
static __device__ __forceinline__ uint4 packbf8(float4 lo, float4 hi) {
    uint4 r;
    r.x = bfpair(lo.x, lo.y); r.y = bfpair(lo.z, lo.w);
    r.z = bfpair(hi.x, hi.y); r.w = bfpair(hi.z, hi.w);
    return r;
}

static __device__ __forceinline__ void gload_lds16(const void* g, void* l) {
    __builtin_amdgcn_global_load_lds((const __attribute__((address_space(1))) void*)g,
                                     (__attribute__((address_space(3))) void*)l, 16, 0, 0);
}

// ---- convert W fp32 -> bf16 (tiny: 1M elems) ----
__global__ void convertW_kernel(const float* __restrict__ W, unsigned short* __restrict__ wb) {
    int t = blockIdx.x * 256 + threadIdx.x;   // 0..262143
    float4 v = ((const float4*)W)[t];
    ushort4 o;
    o.x = f2bf(v.x); o.y = f2bf(v.y); o.z = f2bf(v.z); o.w = f2bf(v.w);
    ((ushort4*)wb)[t] = o;
}

// Stage B half (from pre-converted wb) of a tile into buffer q via global_load_lds.
// LDS linear [256 rows][64 B]; 16B slots XOR-permuted: slot s holds chunk s^((row>>1)&3);
// staging thread's XOR term ((row>>1)&3) == ((lane>>3)&3). Zero-conflict on ds_read
// (verified round 4: SQ_LDS_BANK_CONFLICT = 0).
static __device__ __forceinline__ void stage_B(const unsigned short* __restrict__ Bm, char* smem,
                                               int q, int n0, int ks, int w, int lane) {
    const int c16 = (lane & 3) ^ ((lane >> 3) & 3);
#pragma unroll
    for (int r = 0; r < 2; ++r) {
        int row = r * 128 + w * 16 + (lane >> 2);
        const unsigned short* g = Bm + (size_t)(n0 + row) * DIM + ks + c16 * 8;
        char* l = smem + q * TILE_LDS + 16384 + (r * 128 + w * 16) * 64 + lane * 16;
        gload_lds16(g, l);
    }
}

// ---- GEMM: V[m][n] = bf16( sum_k X[m][k]*W[n][k] + bias[n] ) ----
// A (=X) is fp32 in HBM: reg-staged (load fp32 -> pack bf16 -> ds_write), fusing
// the x-conversion into the GEMM. B from pre-converted wb via global_load_lds.
// 256x256 tile, BK=32, 4-deep LDS rotation, counted vmcnt, 8 waves (2Mx4N).
__global__ __launch_bounds__(512, 2) void gemm_kernel(const float* __restrict__ X,
                                                      const unsigned short* __restrict__ Bm,
                                                      const float* __restrict__ bias,
                                                      unsigned short* __restrict__ V) {
    extern __shared__ char smem[];
    const int tid  = threadIdx.x;
    const int lane = tid & 63;
    const int w    = tid >> 6;           // wave 0..7
    const int wm   = w >> 2;             // 0..1
    const int wn   = w & 3;              // 0..3
    const int wr   = wm * 128;           // wave row offset (M)
    const int wc   = wn * 64;            // wave col offset (N)
    const int rl   = lane & 15;
    const int rh   = lane >> 4;
    const int swz  = (rh ^ ((rl >> 1) & 3)) * 16;  // undo stored XOR permutation
    const int m0   = blockIdx.x * BM;
    const int n0   = blockIdx.y * BN;
    const int c16  = (lane & 3) ^ ((lane >> 3) & 3);
    const int arow = w * 16 + (lane >> 2);                       // 0..127
    const size_t dstA = (size_t)(w * 16) * 64 + (size_t)lane * 16;  // A-half dest (row 0..127 block)

    f32x4 acc[8][4];
#pragma unroll
    for (int m = 0; m < 8; ++m)
#pragma unroll
        for (int n = 0; n < 4; ++n)
            acc[m][n] = (f32x4){0.f, 0.f, 0.f, 0.f};

    float bv[4];
#pragma unroll
    for (int nf = 0; nf < 4; ++nf)
        bv[nf] = bias[n0 + wc + nf * 16 + rl];

    const float* Xa = X + (size_t)(m0 + arow) * DIM + c16 * 8;        // rows arow
    const float* Xb = X + (size_t)(m0 + 128 + arow) * DIM + c16 * 8;  // rows 128+arow

    // aC*: regs holding A data for the tile to be ds_written THIS iteration (tile t+2)
    float4 aCl0, aCh0, aCl1, aCh1;
    float4 aNl0, aNh0, aNl1, aNh1;

    // ---- prologue: fully stage tiles 0,1; load tile 2's A into regs ----
    {
        aCl0 = *(const float4*)(Xa + 0); aCh0 = *(const float4*)(Xa + 4);
        aCl1 = *(const float4*)(Xb + 0); aCh1 = *(const float4*)(Xb + 4);
        *(uint4*)(smem + 0 * TILE_LDS + dstA)             = packbf8(aCl0, aCh0);
        *(uint4*)(smem + 0 * TILE_LDS + 128 * 64 + dstA)  = packbf8(aCl1, aCh1);
        stage_B(Bm, smem, 0, n0, 0, w, lane);
        aCl0 = *(const float4*)(Xa + BK); aCh0 = *(const float4*)(Xa + BK + 4);
        aCl1 = *(const float4*)(Xb + BK); aCh1 = *(const float4*)(Xb + BK + 4);
        *(uint4*)(smem + 1 * TILE_LDS + dstA)             = packbf8(aCl0, aCh0);
        *(uint4*)(smem + 1 * TILE_LDS + 128 * 64 + dstA)  = packbf8(aCl1, aCh1);
        stage_B(Bm, smem, 1, n0, BK, w, lane);
        aCl0 = *(const float4*)(Xa + 2 * BK); aCh0 = *(const float4*)(Xa + 2 * BK + 4);
        aCl1 = *(const float4*)(Xb + 2 * BK); aCh1 = *(const float4*)(Xb + 2 * BK + 4);
    }
    asm volatile("s_waitcnt lgkmcnt(0)" ::: "memory");
    __builtin_amdgcn_s_barrier();

#pragma unroll 4
    for (int t = 0; t < NT; ++t) {
        const int q   = t & 3;
        const int qw  = (t + 2) & 3;                 // buffer written this iter (tile t+2)
        const int ksB = ((t + 2) & (NT - 1)) * BK;   // tail wraps into dead buffers
        const int ksA = ((t + 3) & (NT - 1)) * BK;
        char* base = smem + q * TILE_LDS;

        // (1) issue staging: B->LDS for tile t+2 (2 vmem), A->regs for tile t+3 (4 vmem)
        stage_B(Bm, smem, qw, n0, ksB, w, lane);
        aNl0 = *(const float4*)(Xa + ksA); aNh0 = *(const float4*)(Xa + ksA + 4);
        aNl1 = *(const float4*)(Xb + ksA); aNh1 = *(const float4*)(Xb + ksA + 4);

        // (2) frag reads + MFMA phase A (mf 0..3)
        bf16x8 bfr[4];
#pragma unroll
        for (int nf = 0; nf < 4; ++nf)
            bfr[nf] = *(const bf16x8*)(base + 16384 + (wc + nf * 16 + rl) * 64 + swz);
        bf16x8 af[4];
#pragma unroll
        for (int mf = 0; mf < 4; ++mf)
            af[mf] = *(const bf16x8*)(base + (wr + mf * 16 + rl) * 64 + swz);
        __builtin_amdgcn_s_setprio(1);
#pragma unroll
        for (int mf = 0; mf < 4; ++mf)
#pragma unroll
            for (int nf = 0; nf < 4; ++nf)
                acc[mf][nf] = __builtin_amdgcn_mfma_f32_16x16x32_bf16(af[mf], bfr[nf], acc[mf][nf], 0, 0, 0);
        __builtin_amdgcn_s_setprio(0);

        // (3) pack + ds_write A for tile t+2 (aC loaded one iter ago -> counted vmcnt here)
        *(uint4*)(smem + qw * TILE_LDS + dstA)            = packbf8(aCl0, aCh0);
        *(uint4*)(smem + qw * TILE_LDS + 128 * 64 + dstA) = packbf8(aCl1, aCh1);

        // (4) frag reads + MFMA phase B (mf 4..7, bfr reused)
#pragma unroll
        for (int mf = 0; mf < 4; ++mf)
            af[mf] = *(const bf16x8*)(base + (wr + (mf + 4) * 16 + rl) * 64 + swz);
        __builtin_amdgcn_s_setprio(1);
#pragma unroll
        for (int mf = 0; mf < 4; ++mf)
#pragma unroll
            for (int nf = 0; nf < 4; ++nf)
                acc[mf + 4][nf] = __builtin_amdgcn_mfma_f32_16x16x32_bf16(af[mf], bfr[nf], acc[mf + 4][nf], 0, 0, 0);
        __builtin_amdgcn_s_setprio(0);

        // (5) rotate A regs
        aCl0 = aNl0; aCh0 = aNh0; aCl1 = aNl1; aCh1 = aNh1;

        // tile t+1 residency: B(t+1)/A(t+2) drained by step-3's implicit counted wait;
        // keep 6 newest (B(t+2)x2 + A(t+3)x4) in flight. lgkm drain for cross-wave ds_write.
        asm volatile("s_waitcnt vmcnt(6)" ::: "memory");
        asm volatile("s_waitcnt lgkmcnt(0)" ::: "memory");
        __builtin_amdgcn_sched_barrier(0);
        __builtin_amdgcn_s_barrier();
    }

    // epilogue: C/D layout col = lane&15, row = (lane>>4)*4 + reg; store bf16
#pragma unroll
    for (int mf = 0; mf < 8; ++mf) {
#pragma unroll
        for (int nf = 0; nf < 4; ++nf) {
            int gcol = n0 + wc + nf * 16 + rl;
#pragma unroll
            for (int j = 0; j < 4; ++j) {
                int grow = m0 + wr + mf * 16 + rh * 4 + j;
                V[(size_t)grow * DIM + gcol] = f2bf(acc[mf][nf][j] + bv[nf]);
            }
        }
    }
}

// ---- pass A: per-chunk sums of v*cos, v*sin. 2 e-columns/thread ----
__global__ void passA_kernel(const unsigned short* __restrict__ val, const float* __restrict__ ph,
                             float* __restrict__ pr, float* __restrict__ pi) {
    int t  = blockIdx.x * 256 + threadIdx.x;
    int c  = blockIdx.y;
    int bb = blockIdx.z;
    const ushort2* v = (const ushort2*)val + ((size_t)bb * SEQ + (size_t)c * CL) * (DIM / 2) + t;
    const float2*  p = (const float2*)ph + (size_t)c * CL * (DIM / 2) + t;
    float sr0 = 0.f, si0 = 0.f, sr1 = 0.f, si1 = 0.f;
    for (int l = 0; l < CL; ++l) {
        ushort2 vv = v[(size_t)l * (DIM / 2)];
        float2  pp = p[(size_t)l * (DIM / 2)];
        float v0 = bf2f(vv.x), v1 = bf2f(vv.y);
        float s0, c0, s1, c1;
        __sincosf(pp.x, &s0, &c0);
        __sincosf(pp.y, &s1, &c1);
        sr0 += v0 * c0; si0 += v0 * s0;
        sr1 += v1 * c1; si1 += v1 * s1;
    }
    size_t idx = ((size_t)bb * NC + c) * DIM + 2 * t;
    pr[idx] = sr0; pr[idx + 1] = sr1;
    pi[idx] = si0; pi[idx + 1] = si1;
}

// ---- pass B: exclusive scan of chunk partials over c ----
__global__ void passB_kernel(float* __restrict__ pr, float* __restrict__ pi) {
    int t = blockIdx.x * 256 + threadIdx.x;
    int bb = t >> 10;
    int e  = t & 1023;
    float r = 0.f, im = 0.f;
    for (int c = 0; c < NC; ++c) {
        size_t idx = ((size_t)bb * NC + c) * DIM + e;
        float tr = pr[idx], ti = pi[idx];
        pr[idx] = r; pi[idx] = im;
        r += tr; im += ti;
    }
}

// ---- pass C: running cumsum + retrieval + norm -> fp32 out ----
__global__ void passC_kernel(const unsigned short* __restrict__ val, const float* __restrict__ ph,
                             const float* __restrict__ pr, const float* __restrict__ pi,
                             float* __restrict__ out) {
    int t  = blockIdx.x * 256 + threadIdx.x;
    int c  = blockIdx.y;
    int bb = blockIdx.z;
    size_t base = ((size_t)bb * SEQ + (size_t)c * CL) * (DIM / 2) + t;
    const ushort2* v = (const ushort2*)val + base;
    const float2*  p = (const float2*)ph + (size_t)c * CL * (DIM / 2) + t;
    float2* o = (float2*)out + base;
    size_t pidx = ((size_t)bb * NC + c) * DIM + 2 * t;
    float ar0 = pr[pidx], ar1 = pr[pidx + 1];
    float ai0 = pi[pidx], ai1 = pi[pidx + 1];
    const int l0 = c * CL;
    for (int l = 0; l < CL; ++l) {
        ushort2 vv = v[(size_t)l * (DIM / 2)];
        float2  pp = p[(size_t)l * (DIM / 2)];
        float v0 = bf2f(vv.x), v1 = bf2f(vv.y);
        float s0, c0, s1, c1;
        __sincosf(pp.x, &s0, &c0);
        __sincosf(pp.y, &s1, &c1);
        ar0 += v0 * c0; ai0 += v0 * s0;
        ar1 += v1 * c1; ai1 += v1 * s1;
        float rn = rsqrtf((float)(l0 + l + 1));
        float2 ov;
        ov.x = (ar0 * c0 + ai0 * s0) * rn;
        ov.y = (ar1 * c1 + ai1 * s1) * rn;
        o[(size_t)l * (DIM / 2)] = ov;
    }
}

extern "C" void kernel_launch(void* const* d_in, const int* in_sizes, int n_in,
                              void* d_out, int out_size, void* d_ws, size_t ws_size,
                              hipStream_t stream) {
    const float* x  = (const float*)d_in[0];
    const float* ph = (const float*)d_in[1];
    const float* W  = (const float*)d_in[2];
    const float* b  = (const float*)d_in[3];
    float* out = (float*)d_out;

    // ws: vb bf16 32MB | wb 2MB | pr 256KB | pi 256KB  (~34.5 MB)
    unsigned short* vb = (unsigned short*)d_ws;
    unsigned short* wb = vb + (size_t)MROWS * DIM;
    float* pr = (float*)(wb + (size_t)DIM * DIM);
    float* pi = pr + (size_t)NB * NC * DIM;

    (void)hipFuncSetAttribute((const void*)gemm_kernel,
                              hipFuncAttributeMaxDynamicSharedMemorySize, GEMM_LDS);

    // 1) convert W only (x conversion fused into GEMM staging)
    convertW_kernel<<<DIM * DIM / 4 / 256, 256, 0, stream>>>(W, wb);
    // 2) GEMM (reads fp32 x directly) -> bf16 value into ws
    {
        dim3 grid(MROWS / BM, DIM / BN);
        gemm_kernel<<<grid, 512, GEMM_LDS, stream>>>(x, wb, b, vb);
    }
    // 3) chunk partial sums
    {
        dim3 grid(DIM / 512, NC, NB);
        passA_kernel<<<grid, 256, 0, stream>>>(vb, ph, pr, pi);
    }
    // 4) scan partials
    passB_kernel<<<16, 256, 0, stream>>>(pr, pi);
    // 5) final cumsum + retrieve + norm -> fp32 d_out
    {
        dim3 grid(DIM / 512, NC, NB);
        passC_kernel<<<grid, 256, 0, stream>>>(vb, ph, pr, pi, out);
    }
}